// Round 4
// baseline (6042.344 us; speedup 1.0000x reference)
//
#include <hip/hip_runtime.h>
#include <hip/hip_cooperative_groups.h>
#include <math.h>

namespace cg = cooperative_groups;

#define TT 512
#define DPOI 256
#define DIN 260
#define DHID 356
#define DOUTD 512
#define G3 1536

// GRU partition
#define GRU_BLOCKS 64
#define JPB (DOUTD / GRU_BLOCKS)   // 8 hidden units per block
#define NROWS (3 * JPB)            // 24 w_hh rows per block

// ---------------- feature kernel ----------------
__global__ void feat_kernel(const int* __restrict__ idx, const float* __restrict__ timef,
                            const float* __restrict__ latlon, float* __restrict__ feat) {
    int i = threadIdx.x;
    if (i >= TT) return;
    float t = fminf(fmaxf(timef[i], 0.f), 1.f);
    const float TWO_PI = 6.28318530717958647692f;
    float s = sinf(TWO_PI * t);
    float c = cosf(TWO_PI * t);
    float dt_h = 0.f, dd = 0.f;
    if (i > 0) {
        float tp = fminf(fmaxf(timef[i - 1], 0.f), 1.f);
        float d = t - tp;
        d = d - floorf(d);          // jnp.mod(x, 1.0)
        dt_h = d * 24.f;
        int i0 = idx[i - 1], i1 = idx[i];
        float la0 = latlon[2 * (size_t)i0], lo0 = latlon[2 * (size_t)i0 + 1];
        float la1 = latlon[2 * (size_t)i1], lo1 = latlon[2 * (size_t)i1 + 1];
        const float D2R = 0.01745329251994329577f;
        float lat1 = fminf(fmaxf(la0, -90.f), 90.f) * D2R;
        float lon1 = fminf(fmaxf(lo0, -180.f), 180.f) * D2R;
        float lat2 = fminf(fmaxf(la1, -90.f), 90.f) * D2R;
        float lon2 = fminf(fmaxf(lo1, -180.f), 180.f) * D2R;
        float dlat = (lat2 - lat1) * 0.5f, dlon = (lon2 - lon1) * 0.5f;
        float sdlat = sinf(dlat), sdlon = sinf(dlon);
        float a = sdlat * sdlat +
                  fminf(fmaxf(cosf(lat1), -1.f), 1.f) * fminf(fmaxf(cosf(lat2), -1.f), 1.f) * sdlon * sdlon;
        float aa = fminf(fmaxf(a, 0.f), 1.f);
        float bb = fminf(fmaxf(1.f - a, 1e-12f), 1.f);
        float cc = 2.f * atan2f(sqrtf(aa), sqrtf(bb));
        dd = 6371.0088f * cc;
    }
    feat[4 * i + 0] = s;
    feat[4 * i + 1] = c;
    feat[4 * i + 2] = log1pf(dt_h);
    feat[4 * i + 3] = log1pf(dd);
}

// ---------------- gather + layernorm ----------------
__global__ void ln_kernel(const int* __restrict__ idx, const float* __restrict__ emb,
                          const float* __restrict__ feat, const float* __restrict__ lnw,
                          const float* __restrict__ lnb, float* __restrict__ xn) {
    int t = blockIdx.x;
    int tid = threadIdx.x;           // 256 threads
    int wave = tid >> 6, lane = tid & 63;
    const float* row = emb + (size_t)idx[t] * DPOI;
    float v0 = row[tid];
    float v1 = (tid < 4) ? feat[4 * t + tid] : 0.f;

    __shared__ float red[4];
    __shared__ float mu_s, rs_s;

    float s = v0 + v1;
    for (int o = 32; o; o >>= 1) s += __shfl_down(s, o, 64);
    if (lane == 0) red[wave] = s;
    __syncthreads();
    if (tid == 0) mu_s = (red[0] + red[1] + red[2] + red[3]) * (1.f / 260.f);
    __syncthreads();
    float mu = mu_s;
    float d0 = v0 - mu;
    float d1 = (tid < 4) ? (v1 - mu) : 0.f;
    float sq = d0 * d0 + d1 * d1;
    for (int o = 32; o; o >>= 1) sq += __shfl_down(sq, o, 64);
    __syncthreads();
    if (lane == 0) red[wave] = sq;
    __syncthreads();
    if (tid == 0) {
        float var = (red[0] + red[1] + red[2] + red[3]) * (1.f / 260.f);
        rs_s = rsqrtf(var + 1e-5f);
    }
    __syncthreads();
    float rs = rs_s;
    xn[t * DIN + tid] = d0 * rs * lnw[tid] + lnb[tid];
    if (tid < 4)
        xn[t * DIN + 256 + tid] = d1 * rs * lnw[256 + tid] + lnb[256 + tid];
}

// ---------------- x @ w1 + b1, gelu ----------------
__global__ void mlp1_kernel(const float* __restrict__ xn, const float* __restrict__ w1,
                            const float* __restrict__ b1, float* __restrict__ h1) {
    int t = blockIdx.x, j = threadIdx.x;   // 384 threads
    __shared__ float xl[DIN];
    for (int k = threadIdx.x; k < DIN; k += blockDim.x) xl[k] = xn[t * DIN + k];
    __syncthreads();
    if (j < DHID) {
        float acc = b1[j];
        #pragma unroll 4
        for (int k = 0; k < DIN; ++k) acc = fmaf(xl[k], w1[k * DHID + j], acc);
        float g = 0.5f * acc * (1.f + erff(acc * 0.70710678118654752440f));
        h1[t * DHID + j] = g;
    }
}

// ---------------- h1 @ w2 + b2 ----------------
__global__ void mlp2_kernel(const float* __restrict__ h1, const float* __restrict__ w2,
                            const float* __restrict__ b2, float* __restrict__ x2) {
    int t = blockIdx.x, j = threadIdx.x;   // 256 threads
    __shared__ float xl[DHID];
    for (int k = threadIdx.x; k < DHID; k += blockDim.x) xl[k] = h1[t * DHID + k];
    __syncthreads();
    float acc = b2[j];
    #pragma unroll 4
    for (int k = 0; k < DHID; ++k) acc = fmaf(xl[k], w2[k * DPOI + j], acc);
    x2[t * DPOI + j] = acc;
}

// ---------------- gi = x2 @ w_ih.T + b_ih ----------------
__global__ void gi_kernel(const float* __restrict__ x2, const float* __restrict__ wih,
                          const float* __restrict__ bih, float* __restrict__ gi) {
    int t = blockIdx.x;
    int tid = threadIdx.x;   // 256
    int wave = tid >> 6, lane = tid & 63;
    float4 xv = ((const float4*)(x2 + (size_t)t * DPOI))[lane];
    for (int r = wave; r < G3; r += 4) {
        float4 wv = ((const float4*)(wih + (size_t)r * DPOI))[lane];
        float s = xv.x * wv.x + xv.y * wv.y + xv.z * wv.z + xv.w * wv.w;
        for (int o = 32; o; o >>= 1) s += __shfl_down(s, o, 64);
        if (lane == 0) gi[(size_t)t * G3 + r] = s + bih[r];
    }
}

// ---------------- GRU scan: cooperative kernel, one grid.sync per step ----------------
__global__ __launch_bounds__(256)
void gru_coop_kernel(const float* __restrict__ gi, const float* __restrict__ whh,
                     const float* __restrict__ bhh, float* __restrict__ hs) {
    cg::grid_group grid = cg::this_grid();

    __shared__ float w[NROWS][DOUTD];   // 24*512*4 = 49152 B
    __shared__ float hprev[DOUTD];      // 2 KB
    __shared__ float gsum[NROWS];
    __shared__ float bl[NROWS];

    int b = blockIdx.x;        // 0..63
    int tid = threadIdx.x;     // 256
    int wave = tid >> 6, lane = tid & 63;
    int jbase = b * JPB;

    // load my 24 rows of w_hh (rows g*512 + jbase + jj)
    for (int rr = 0; rr < NROWS; ++rr) {
        int g = rr / JPB, jj = rr % JPB;
        size_t grow = (size_t)(g * DOUTD + jbase + jj) * DOUTD;
        for (int k = tid; k < DOUTD; k += 256) w[rr][k] = whh[grow + k];
    }
    if (tid < NROWS) {
        int g = tid / JPB, jj = tid % JPB;
        bl[tid] = bhh[g * DOUTD + jbase + jj];
    }
    for (int k = tid; k < DOUTD; k += 256) hprev[k] = 0.f;
    __syncthreads();

    for (int s = 0; s < TT; ++s) {
        if (s > 0) {
            // hs row s-1 is visible after the previous grid.sync()
            for (int k = tid; k < DOUTD; k += 256)
                hprev[k] = hs[(size_t)(s - 1) * DOUTD + k];
            __syncthreads();
        }
        // 24 rows over 4 waves -> 6 rows/wave
        #pragma unroll
        for (int rv = 0; rv < 6; ++rv) {
            int rr = wave * 6 + rv;
            float acc = 0.f;
            #pragma unroll
            for (int m = 0; m < 8; ++m) {
                int k = lane + 64 * m;
                acc = fmaf(w[rr][k], hprev[k], acc);
            }
            for (int o = 32; o; o >>= 1) acc += __shfl_down(acc, o, 64);
            if (lane == 0) gsum[rr] = acc + bl[rr];
        }
        __syncthreads();
        if (tid < JPB) {
            int j = jbase + tid;
            float gr = gi[(size_t)s * G3 + j] + gsum[0 * JPB + tid];
            float gz = gi[(size_t)s * G3 + DOUTD + j] + gsum[1 * JPB + tid];
            float gni = gi[(size_t)s * G3 + 2 * DOUTD + j];
            float ghn = gsum[2 * JPB + tid];
            float r = 1.f / (1.f + expf(-gr));
            float z = 1.f / (1.f + expf(-gz));
            float n = tanhf(gni + r * ghn);
            float hn = (1.f - z) * n + z * hprev[j];
            hs[(size_t)s * DOUTD + j] = hn;
        }
        // one barrier per step: step s+1 reads row s (disjoint from row s-1 reads)
        grid.sync();
    }
}

// ---------------- attention epilogue ----------------
__global__ void attn_kernel(const float* __restrict__ hs, const float* __restrict__ q,
                            const float* __restrict__ log_lam, float* __restrict__ out) {
    int tid = threadIdx.x;   // 512
    int wave = tid >> 6, lane = tid & 63;
    __shared__ float sc[TT];
    __shared__ float at[TT];
    __shared__ float red[8];
    __shared__ float red2[8];
    __shared__ float denom_s, mx_s;

    const float qscale = 0.04419417382415921757f;  // 1/sqrt(512)
    for (int r = wave; r < TT; r += 8) {
        float acc = 0.f;
        #pragma unroll
        for (int m = 0; m < 8; ++m) {
            int k = lane + 64 * m;
            acc = fmaf(hs[(size_t)r * DOUTD + k], q[k], acc);
        }
        for (int o = 32; o; o >>= 1) acc += __shfl_down(acc, o, 64);
        if (lane == 0) sc[r] = acc * qscale;
    }
    __syncthreads();
    float lam = fmaxf(expf(log_lam[0]), 1e-4f);
    float s_i = sc[tid] - lam * (float)(TT - 1 - tid);

    float mval = s_i;
    for (int o = 32; o; o >>= 1) mval = fmaxf(mval, __shfl_down(mval, o, 64));
    if (lane == 0) red[wave] = mval;
    __syncthreads();
    if (tid == 0) {
        float mm = red[0];
        for (int i = 1; i < 8; ++i) mm = fmaxf(mm, red[i]);
        mx_s = mm;
    }
    __syncthreads();
    float e = expf(s_i - mx_s);
    float ssum = e;
    for (int o = 32; o; o >>= 1) ssum += __shfl_down(ssum, o, 64);
    if (lane == 0) red2[wave] = ssum;
    __syncthreads();
    if (tid == 0) {
        float dsum = 0.f;
        for (int i = 0; i < 8; ++i) dsum += red2[i];
        denom_s = dsum;
    }
    __syncthreads();
    float attn = e / denom_s;
    out[DOUTD + tid] = attn;     // output 1: attn (T,)
    at[tid] = attn;
    __syncthreads();
    // summary[d]: coalesced across d for each row i
    float acc = 0.f;
    for (int i = 0; i < TT; ++i) acc = fmaf(at[i], hs[(size_t)i * DOUTD + tid], acc);
    out[tid] = acc;              // output 0: summary (1, 512)
}

extern "C" void kernel_launch(void* const* d_in, const int* in_sizes, int n_in,
                              void* d_out, int out_size, void* d_ws, size_t ws_size,
                              hipStream_t stream) {
    const int*   idx    = (const int*)d_in[0];
    const float* timef  = (const float*)d_in[1];
    const float* emb    = (const float*)d_in[2];
    const float* latlon = (const float*)d_in[3];
    const float* lnw    = (const float*)d_in[4];
    const float* lnb    = (const float*)d_in[5];
    const float* w1     = (const float*)d_in[6];
    const float* b1     = (const float*)d_in[7];
    const float* w2     = (const float*)d_in[8];
    const float* b2     = (const float*)d_in[9];
    const float* wih    = (const float*)d_in[10];  // (1536, 256)
    const float* whh    = (const float*)d_in[11];  // (1536, 512)
    const float* bih    = (const float*)d_in[12];  // (1536,)
    const float* bhh    = (const float*)d_in[13];  // (1536,)
    const float* q      = (const float*)d_in[14];
    const float* loglam = (const float*)d_in[15];
    float* out = (float*)d_out;

    float* ws   = (float*)d_ws;
    float* feat = ws;                       // 2048
    float* xn   = feat + 2048;              // 512*260 = 133120
    float* h1   = xn + 133120;              // 512*356 = 182272
    float* x2   = h1 + 182272;              // 512*256 = 131072
    float* gi   = x2 + 131072;              // 512*1536 = 786432
    float* hs   = gi + 786432;              // 512*512 = 262144

    feat_kernel<<<1, TT, 0, stream>>>(idx, timef, latlon, feat);
    ln_kernel<<<TT, 256, 0, stream>>>(idx, emb, feat, lnw, lnb, xn);
    mlp1_kernel<<<TT, 384, 0, stream>>>(xn, w1, b1, h1);
    mlp2_kernel<<<TT, 256, 0, stream>>>(h1, w2, b2, x2);
    gi_kernel<<<TT, 256, 0, stream>>>(x2, wih, bih, gi);

    void* gru_args[] = { (void*)&gi, (void*)&whh, (void*)&bhh, (void*)&hs };
    hipLaunchCooperativeKernel((void*)gru_coop_kernel, dim3(GRU_BLOCKS), dim3(256),
                               gru_args, 0, stream);

    attn_kernel<<<1, TT, 0, stream>>>(hs, q, loglam, out);
}

// Round 5
// 5936.718 us; speedup vs baseline: 1.0178x; 1.0178x over previous
//
#include <hip/hip_runtime.h>
#include <hip/hip_cooperative_groups.h>
#include <math.h>

namespace cg = cooperative_groups;

#define TT 512
#define DPOI 256
#define DIN 260
#define DHID 356
#define DOUTD 512
#define G3 1536

// GRU partition: 16 blocks x 1024 threads, 32 hidden units per block
#define GB 16
#define JPB (DOUTD / GB)     // 32 hidden units per block
#define NR (3 * JPB)         // 96 w_hh rows per block (bf16 in LDS: 96 KB)
#define FLAG_STRIDE 64       // ints; 256 B between flag slots

// ---------------- feature kernel ----------------
__global__ void feat_kernel(const int* __restrict__ idx, const float* __restrict__ timef,
                            const float* __restrict__ latlon, float* __restrict__ feat) {
    int i = threadIdx.x;
    if (i >= TT) return;
    float t = fminf(fmaxf(timef[i], 0.f), 1.f);
    const float TWO_PI = 6.28318530717958647692f;
    float s = sinf(TWO_PI * t);
    float c = cosf(TWO_PI * t);
    float dt_h = 0.f, dd = 0.f;
    if (i > 0) {
        float tp = fminf(fmaxf(timef[i - 1], 0.f), 1.f);
        float d = t - tp;
        d = d - floorf(d);          // jnp.mod(x, 1.0)
        dt_h = d * 24.f;
        int i0 = idx[i - 1], i1 = idx[i];
        float la0 = latlon[2 * (size_t)i0], lo0 = latlon[2 * (size_t)i0 + 1];
        float la1 = latlon[2 * (size_t)i1], lo1 = latlon[2 * (size_t)i1 + 1];
        const float D2R = 0.01745329251994329577f;
        float lat1 = fminf(fmaxf(la0, -90.f), 90.f) * D2R;
        float lon1 = fminf(fmaxf(lo0, -180.f), 180.f) * D2R;
        float lat2 = fminf(fmaxf(la1, -90.f), 90.f) * D2R;
        float lon2 = fminf(fmaxf(lo1, -180.f), 180.f) * D2R;
        float dlat = (lat2 - lat1) * 0.5f, dlon = (lon2 - lon1) * 0.5f;
        float sdlat = sinf(dlat), sdlon = sinf(dlon);
        float a = sdlat * sdlat +
                  fminf(fmaxf(cosf(lat1), -1.f), 1.f) * fminf(fmaxf(cosf(lat2), -1.f), 1.f) * sdlon * sdlon;
        float aa = fminf(fmaxf(a, 0.f), 1.f);
        float bb = fminf(fmaxf(1.f - a, 1e-12f), 1.f);
        float cc = 2.f * atan2f(sqrtf(aa), sqrtf(bb));
        dd = 6371.0088f * cc;
    }
    feat[4 * i + 0] = s;
    feat[4 * i + 1] = c;
    feat[4 * i + 2] = log1pf(dt_h);
    feat[4 * i + 3] = log1pf(dd);
}

// ---------------- gather + layernorm ----------------
__global__ void ln_kernel(const int* __restrict__ idx, const float* __restrict__ emb,
                          const float* __restrict__ feat, const float* __restrict__ lnw,
                          const float* __restrict__ lnb, float* __restrict__ xn) {
    int t = blockIdx.x;
    int tid = threadIdx.x;           // 256 threads
    int wave = tid >> 6, lane = tid & 63;
    const float* row = emb + (size_t)idx[t] * DPOI;
    float v0 = row[tid];
    float v1 = (tid < 4) ? feat[4 * t + tid] : 0.f;

    __shared__ float red[4];
    __shared__ float mu_s, rs_s;

    float s = v0 + v1;
    for (int o = 32; o; o >>= 1) s += __shfl_down(s, o, 64);
    if (lane == 0) red[wave] = s;
    __syncthreads();
    if (tid == 0) mu_s = (red[0] + red[1] + red[2] + red[3]) * (1.f / 260.f);
    __syncthreads();
    float mu = mu_s;
    float d0 = v0 - mu;
    float d1 = (tid < 4) ? (v1 - mu) : 0.f;
    float sq = d0 * d0 + d1 * d1;
    for (int o = 32; o; o >>= 1) sq += __shfl_down(sq, o, 64);
    __syncthreads();
    if (lane == 0) red[wave] = sq;
    __syncthreads();
    if (tid == 0) {
        float var = (red[0] + red[1] + red[2] + red[3]) * (1.f / 260.f);
        rs_s = rsqrtf(var + 1e-5f);
    }
    __syncthreads();
    float rs = rs_s;
    xn[t * DIN + tid] = d0 * rs * lnw[tid] + lnb[tid];
    if (tid < 4)
        xn[t * DIN + 256 + tid] = d1 * rs * lnw[256 + tid] + lnb[256 + tid];
}

// ---------------- x @ w1 + b1, gelu ----------------
__global__ void mlp1_kernel(const float* __restrict__ xn, const float* __restrict__ w1,
                            const float* __restrict__ b1, float* __restrict__ h1) {
    int t = blockIdx.x, j = threadIdx.x;   // 384 threads
    __shared__ float xl[DIN];
    for (int k = threadIdx.x; k < DIN; k += blockDim.x) xl[k] = xn[t * DIN + k];
    __syncthreads();
    if (j < DHID) {
        float acc = b1[j];
        #pragma unroll 4
        for (int k = 0; k < DIN; ++k) acc = fmaf(xl[k], w1[k * DHID + j], acc);
        float g = 0.5f * acc * (1.f + erff(acc * 0.70710678118654752440f));
        h1[t * DHID + j] = g;
    }
}

// ---------------- h1 @ w2 + b2 ----------------
__global__ void mlp2_kernel(const float* __restrict__ h1, const float* __restrict__ w2,
                            const float* __restrict__ b2, float* __restrict__ x2) {
    int t = blockIdx.x, j = threadIdx.x;   // 256 threads
    __shared__ float xl[DHID];
    for (int k = threadIdx.x; k < DHID; k += blockDim.x) xl[k] = h1[t * DHID + k];
    __syncthreads();
    float acc = b2[j];
    #pragma unroll 4
    for (int k = 0; k < DHID; ++k) acc = fmaf(xl[k], w2[k * DPOI + j], acc);
    x2[t * DPOI + j] = acc;
}

// ---------------- gi = x2 @ w_ih.T + b_ih ----------------
__global__ void gi_kernel(const float* __restrict__ x2, const float* __restrict__ wih,
                          const float* __restrict__ bih, float* __restrict__ gi) {
    int t = blockIdx.x;
    int tid = threadIdx.x;   // 256
    int wave = tid >> 6, lane = tid & 63;
    float4 xv = ((const float4*)(x2 + (size_t)t * DPOI))[lane];
    for (int r = wave; r < G3; r += 4) {
        float4 wv = ((const float4*)(wih + (size_t)r * DPOI))[lane];
        float s = xv.x * wv.x + xv.y * wv.y + xv.z * wv.z + xv.w * wv.w;
        for (int o = 32; o; o >>= 1) s += __shfl_down(s, o, 64);
        if (lane == 0) gi[(size_t)t * G3 + r] = s + bih[r];
    }
}

// ---------------- zero flags ----------------
__global__ void zero_kernel(int* __restrict__ c, int n) {
    int i = blockIdx.x * blockDim.x + threadIdx.x;
    if (i < n) c[i] = 0;
}

// ---------------- GRU scan: 16 blocks, data-as-flag decentralized barrier ----------------
// Block b owns hidden units [b*32, b*32+32). w_hh slice (96 rows x 512) lives in LDS
// as bf16 (96 KB). After step s, block b release-stores flags[b*64] = s+1; at step s,
// wave w of every block acquire-spins on flags[w*64] >= s then loads producer w's chunk.
__global__ __launch_bounds__(1024)
void gru_flag_kernel(const float* __restrict__ gi, const float* __restrict__ whh,
                     const float* __restrict__ bhh, float* __restrict__ hs,
                     int* __restrict__ flags) {
    __shared__ unsigned short w[NR][DOUTD];   // 96*512*2 = 98304 B
    __shared__ float hprev[DOUTD];            // 2 KB
    __shared__ float gsum[NR];
    __shared__ float bl[NR];

    int b = blockIdx.x;        // 0..15
    int tid = threadIdx.x;     // 0..1023
    int wave = tid >> 6, lane = tid & 63;
    int jbase = b * JPB;

    // stage my 96 rows of w_hh, RNE-rounded to bf16.
    // row rr (= g*32+jj) <- whh row g*512 + jbase + jj
    for (int e = tid; e < NR * DOUTD; e += 1024) {
        int rr = e >> 9, k = e & 511;
        int g = rr / JPB, jj = rr % JPB;
        float v = whh[(size_t)(g * DOUTD + jbase + jj) * DOUTD + k];
        unsigned int u = __float_as_uint(v);
        u += 0x7fffu + ((u >> 16) & 1u);      // round-to-nearest-even
        w[rr][k] = (unsigned short)(u >> 16);
    }
    if (tid < NR) {
        int g = tid / JPB, jj = tid % JPB;
        bl[tid] = bhh[g * DOUTD + jbase + jj];
    }
    for (int k = tid; k < DOUTD; k += 1024) hprev[k] = 0.f;
    __syncthreads();

    long budget = 25L * 1000 * 1000;   // kernel-lifetime spin budget (fail-safe, ~1 s)

    for (int s = 0; s < TT; ++s) {
        if (s > 0) {
            // wave `wave` is responsible for producer block bb = wave
            int bb = wave;
            if (lane == 0) {
                while (__hip_atomic_load(&flags[bb * FLAG_STRIDE], __ATOMIC_ACQUIRE,
                                         __HIP_MEMORY_SCOPE_AGENT) < s) {
                    __builtin_amdgcn_s_sleep(1);
                    if (--budget < 0) break;   // converts any deadlock into numeric fail
                }
            }
            // lane0's acquire (cache-inv) precedes the wave's loads in program order
            if (lane < JPB) {
                int kk = bb * JPB + lane;
                hprev[kk] = hs[(size_t)(s - 1) * DOUTD + kk];
            }
            __syncthreads();   // barrier A: all chunks in hprev
        }

        // matvec: 96 rows over 16 waves -> 6 rows/wave
        #pragma unroll
        for (int rv = 0; rv < 6; ++rv) {
            int rr = wave * 6 + rv;
            float acc = 0.f;
            #pragma unroll
            for (int m = 0; m < 8; ++m) {
                int k = lane + (m << 6);
                float wv = __uint_as_float((unsigned int)w[rr][k] << 16);
                acc = fmaf(wv, hprev[k], acc);
            }
            for (int o = 32; o; o >>= 1) acc += __shfl_down(acc, o, 64);
            if (lane == 0) gsum[rr] = acc + bl[rr];
        }
        // snapshot own h before barrier B (next step's hprev writes are pre-A and
        // could overwrite hprev[jbase..] while wave 0 runs the gate code post-B)
        float hown = (tid < JPB) ? hprev[jbase + tid] : 0.f;
        __syncthreads();       // barrier B: gsum complete; no hprev reads after this

        if (tid < JPB) {       // wave 0, lanes 0..31
            int j = jbase + tid;
            const float* girow = gi + (size_t)s * G3;
            float gr  = girow[j]             + gsum[tid];
            float gz  = girow[DOUTD + j]     + gsum[JPB + tid];
            float gni = girow[2 * DOUTD + j];
            float ghn = gsum[2 * JPB + tid];
            float r = 1.f / (1.f + expf(-gr));
            float z = 1.f / (1.f + expf(-gz));
            float n = tanhf(gni + r * ghn);
            float hn = (1.f - z) * n + z * hown;
            hs[(size_t)s * DOUTD + j] = hn;
        }
        // release: same wave (wave 0) as the hs stores -> program order guarantees
        // the 32 stores precede the flag store; RELEASE+AGENT publishes them.
        if (tid == 0) {
            __hip_atomic_store(&flags[b * FLAG_STRIDE], s + 1, __ATOMIC_RELEASE,
                               __HIP_MEMORY_SCOPE_AGENT);
        }
        // no global barrier: fast blocks wait on flags, rows of hs never reused
    }
}

// ---------------- attention epilogue ----------------
__global__ void attn_kernel(const float* __restrict__ hs, const float* __restrict__ q,
                            const float* __restrict__ log_lam, float* __restrict__ out) {
    int tid = threadIdx.x;   // 512
    int wave = tid >> 6, lane = tid & 63;
    __shared__ float sc[TT];
    __shared__ float at[TT];
    __shared__ float red[8];
    __shared__ float red2[8];
    __shared__ float denom_s, mx_s;

    const float qscale = 0.04419417382415921757f;  // 1/sqrt(512)
    for (int r = wave; r < TT; r += 8) {
        float acc = 0.f;
        #pragma unroll
        for (int m = 0; m < 8; ++m) {
            int k = lane + 64 * m;
            acc = fmaf(hs[(size_t)r * DOUTD + k], q[k], acc);
        }
        for (int o = 32; o; o >>= 1) acc += __shfl_down(acc, o, 64);
        if (lane == 0) sc[r] = acc * qscale;
    }
    __syncthreads();
    float lam = fmaxf(expf(log_lam[0]), 1e-4f);
    float s_i = sc[tid] - lam * (float)(TT - 1 - tid);

    float mval = s_i;
    for (int o = 32; o; o >>= 1) mval = fmaxf(mval, __shfl_down(mval, o, 64));
    if (lane == 0) red[wave] = mval;
    __syncthreads();
    if (tid == 0) {
        float mm = red[0];
        for (int i = 1; i < 8; ++i) mm = fmaxf(mm, red[i]);
        mx_s = mm;
    }
    __syncthreads();
    float e = expf(s_i - mx_s);
    float ssum = e;
    for (int o = 32; o; o >>= 1) ssum += __shfl_down(ssum, o, 64);
    if (lane == 0) red2[wave] = ssum;
    __syncthreads();
    if (tid == 0) {
        float dsum = 0.f;
        for (int i = 0; i < 8; ++i) dsum += red2[i];
        denom_s = dsum;
    }
    __syncthreads();
    float attn = e / denom_s;
    out[DOUTD + tid] = attn;     // output 1: attn (T,)
    at[tid] = attn;
    __syncthreads();
    // summary[d]: coalesced across d for each row i
    float acc = 0.f;
    for (int i = 0; i < TT; ++i) acc = fmaf(at[i], hs[(size_t)i * DOUTD + tid], acc);
    out[tid] = acc;              // output 0: summary (1, 512)
}

extern "C" void kernel_launch(void* const* d_in, const int* in_sizes, int n_in,
                              void* d_out, int out_size, void* d_ws, size_t ws_size,
                              hipStream_t stream) {
    const int*   idx    = (const int*)d_in[0];
    const float* timef  = (const float*)d_in[1];
    const float* emb    = (const float*)d_in[2];
    const float* latlon = (const float*)d_in[3];
    const float* lnw    = (const float*)d_in[4];
    const float* lnb    = (const float*)d_in[5];
    const float* w1     = (const float*)d_in[6];
    const float* b1     = (const float*)d_in[7];
    const float* w2     = (const float*)d_in[8];
    const float* b2     = (const float*)d_in[9];
    const float* wih    = (const float*)d_in[10];  // (1536, 256)
    const float* whh    = (const float*)d_in[11];  // (1536, 512)
    const float* bih    = (const float*)d_in[12];  // (1536,)
    const float* bhh    = (const float*)d_in[13];  // (1536,)
    const float* q      = (const float*)d_in[14];
    const float* loglam = (const float*)d_in[15];
    float* out = (float*)d_out;

    int*   flags = (int*)d_ws;              // GB*FLAG_STRIDE ints = 4 KB
    float* ws   = (float*)d_ws + GB * FLAG_STRIDE;
    float* feat = ws;                       // 2048
    float* xn   = feat + 2048;              // 512*260 = 133120
    float* h1   = xn + 133120;              // 512*356 = 182272
    float* x2   = h1 + 182272;              // 512*256 = 131072
    float* gi   = x2 + 131072;              // 512*1536 = 786432
    float* hs   = gi + 786432;              // 512*512 = 262144

    feat_kernel<<<1, TT, 0, stream>>>(idx, timef, latlon, feat);
    ln_kernel<<<TT, 256, 0, stream>>>(idx, emb, feat, lnw, lnb, xn);
    mlp1_kernel<<<TT, 384, 0, stream>>>(xn, w1, b1, h1);
    mlp2_kernel<<<TT, 256, 0, stream>>>(h1, w2, b2, x2);
    gi_kernel<<<TT, 256, 0, stream>>>(x2, wih, bih, gi);
    zero_kernel<<<1, GB * FLAG_STRIDE, 0, stream>>>(flags, GB * FLAG_STRIDE);

    void* gru_args[] = { (void*)&gi, (void*)&whh, (void*)&bhh, (void*)&hs, (void*)&flags };
    hipLaunchCooperativeKernel((void*)gru_flag_kernel, dim3(GB), dim3(1024),
                               gru_args, 0, stream);

    attn_kernel<<<1, TT, 0, stream>>>(hs, q, loglam, out);
}

// Round 6
// 3024.789 us; speedup vs baseline: 1.9976x; 1.9627x over previous
//
#include <hip/hip_runtime.h>
#include <hip/hip_cooperative_groups.h>
#include <math.h>

namespace cg = cooperative_groups;

#define TT 512
#define DPOI 256
#define DIN 260
#define DHID 356
#define DOUTD 512
#define G3 1536

// GRU partition: 16 blocks x 1024 threads, 32 hidden units per block
#define GB 16
#define JPB (DOUTD / GB)     // 32 hidden units per block
#define NR (3 * JPB)         // 96 w_hh rows per block (bf16 in LDS: 96 KB)
#define FLAG_STRIDE 64       // ints; 256 B between flag slots

// ---------------- feature kernel ----------------
__global__ void feat_kernel(const int* __restrict__ idx, const float* __restrict__ timef,
                            const float* __restrict__ latlon, float* __restrict__ feat) {
    int i = threadIdx.x;
    if (i >= TT) return;
    float t = fminf(fmaxf(timef[i], 0.f), 1.f);
    const float TWO_PI = 6.28318530717958647692f;
    float s = sinf(TWO_PI * t);
    float c = cosf(TWO_PI * t);
    float dt_h = 0.f, dd = 0.f;
    if (i > 0) {
        float tp = fminf(fmaxf(timef[i - 1], 0.f), 1.f);
        float d = t - tp;
        d = d - floorf(d);          // jnp.mod(x, 1.0)
        dt_h = d * 24.f;
        int i0 = idx[i - 1], i1 = idx[i];
        float la0 = latlon[2 * (size_t)i0], lo0 = latlon[2 * (size_t)i0 + 1];
        float la1 = latlon[2 * (size_t)i1], lo1 = latlon[2 * (size_t)i1 + 1];
        const float D2R = 0.01745329251994329577f;
        float lat1 = fminf(fmaxf(la0, -90.f), 90.f) * D2R;
        float lon1 = fminf(fmaxf(lo0, -180.f), 180.f) * D2R;
        float lat2 = fminf(fmaxf(la1, -90.f), 90.f) * D2R;
        float lon2 = fminf(fmaxf(lo1, -180.f), 180.f) * D2R;
        float dlat = (lat2 - lat1) * 0.5f, dlon = (lon2 - lon1) * 0.5f;
        float sdlat = sinf(dlat), sdlon = sinf(dlon);
        float a = sdlat * sdlat +
                  fminf(fmaxf(cosf(lat1), -1.f), 1.f) * fminf(fmaxf(cosf(lat2), -1.f), 1.f) * sdlon * sdlon;
        float aa = fminf(fmaxf(a, 0.f), 1.f);
        float bb = fminf(fmaxf(1.f - a, 1e-12f), 1.f);
        float cc = 2.f * atan2f(sqrtf(aa), sqrtf(bb));
        dd = 6371.0088f * cc;
    }
    feat[4 * i + 0] = s;
    feat[4 * i + 1] = c;
    feat[4 * i + 2] = log1pf(dt_h);
    feat[4 * i + 3] = log1pf(dd);
}

// ---------------- gather + layernorm ----------------
__global__ void ln_kernel(const int* __restrict__ idx, const float* __restrict__ emb,
                          const float* __restrict__ feat, const float* __restrict__ lnw,
                          const float* __restrict__ lnb, float* __restrict__ xn) {
    int t = blockIdx.x;
    int tid = threadIdx.x;           // 256 threads
    int wave = tid >> 6, lane = tid & 63;
    const float* row = emb + (size_t)idx[t] * DPOI;
    float v0 = row[tid];
    float v1 = (tid < 4) ? feat[4 * t + tid] : 0.f;

    __shared__ float red[4];
    __shared__ float mu_s, rs_s;

    float s = v0 + v1;
    for (int o = 32; o; o >>= 1) s += __shfl_down(s, o, 64);
    if (lane == 0) red[wave] = s;
    __syncthreads();
    if (tid == 0) mu_s = (red[0] + red[1] + red[2] + red[3]) * (1.f / 260.f);
    __syncthreads();
    float mu = mu_s;
    float d0 = v0 - mu;
    float d1 = (tid < 4) ? (v1 - mu) : 0.f;
    float sq = d0 * d0 + d1 * d1;
    for (int o = 32; o; o >>= 1) sq += __shfl_down(sq, o, 64);
    __syncthreads();
    if (lane == 0) red[wave] = sq;
    __syncthreads();
    if (tid == 0) {
        float var = (red[0] + red[1] + red[2] + red[3]) * (1.f / 260.f);
        rs_s = rsqrtf(var + 1e-5f);
    }
    __syncthreads();
    float rs = rs_s;
    xn[t * DIN + tid] = d0 * rs * lnw[tid] + lnb[tid];
    if (tid < 4)
        xn[t * DIN + 256 + tid] = d1 * rs * lnw[256 + tid] + lnb[256 + tid];
}

// ---------------- x @ w1 + b1, gelu ----------------
__global__ void mlp1_kernel(const float* __restrict__ xn, const float* __restrict__ w1,
                            const float* __restrict__ b1, float* __restrict__ h1) {
    int t = blockIdx.x, j = threadIdx.x;   // 384 threads
    __shared__ float xl[DIN];
    for (int k = threadIdx.x; k < DIN; k += blockDim.x) xl[k] = xn[t * DIN + k];
    __syncthreads();
    if (j < DHID) {
        float acc = b1[j];
        #pragma unroll 4
        for (int k = 0; k < DIN; ++k) acc = fmaf(xl[k], w1[k * DHID + j], acc);
        float g = 0.5f * acc * (1.f + erff(acc * 0.70710678118654752440f));
        h1[t * DHID + j] = g;
    }
}

// ---------------- h1 @ w2 + b2 ----------------
__global__ void mlp2_kernel(const float* __restrict__ h1, const float* __restrict__ w2,
                            const float* __restrict__ b2, float* __restrict__ x2) {
    int t = blockIdx.x, j = threadIdx.x;   // 256 threads
    __shared__ float xl[DHID];
    for (int k = threadIdx.x; k < DHID; k += blockDim.x) xl[k] = h1[t * DHID + k];
    __syncthreads();
    float acc = b2[j];
    #pragma unroll 4
    for (int k = 0; k < DHID; ++k) acc = fmaf(xl[k], w2[k * DPOI + j], acc);
    x2[t * DPOI + j] = acc;
}

// ---------------- gi = x2 @ w_ih.T + b_ih ----------------
__global__ void gi_kernel(const float* __restrict__ x2, const float* __restrict__ wih,
                          const float* __restrict__ bih, float* __restrict__ gi) {
    int t = blockIdx.x;
    int tid = threadIdx.x;   // 256
    int wave = tid >> 6, lane = tid & 63;
    float4 xv = ((const float4*)(x2 + (size_t)t * DPOI))[lane];
    for (int r = wave; r < G3; r += 4) {
        float4 wv = ((const float4*)(wih + (size_t)r * DPOI))[lane];
        float s = xv.x * wv.x + xv.y * wv.y + xv.z * wv.z + xv.w * wv.w;
        for (int o = 32; o; o >>= 1) s += __shfl_down(s, o, 64);
        if (lane == 0) gi[(size_t)t * G3 + r] = s + bih[r];
    }
}

// ---------------- zero flags ----------------
__global__ void zero_kernel(int* __restrict__ c, int n) {
    int i = blockIdx.x * blockDim.x + threadIdx.x;
    if (i < n) c[i] = 0;
}

// ---------------- GRU scan: relaxed-atomic data-as-flag barrier, busy poll ----------------
// All cross-block traffic uses RELAXED agent-scope atomics (plain loads/stores with
// L1/L2-bypass cache bits -> NO buffer_wbl2 / cache-invalidate per op). Ordering
// producer-side via one explicit s_waitcnt vmcnt(0) between hs stores and flag store
// (same wave, program order). Busy poll (no s_sleep) keeps clocks up.
__global__ __launch_bounds__(1024)
void gru_flag_kernel(const float* __restrict__ gi, const float* __restrict__ whh,
                     const float* __restrict__ bhh, float* __restrict__ hs,
                     int* __restrict__ flags) {
    __shared__ unsigned short w[NR][DOUTD];   // 96*512*2 = 98304 B
    __shared__ float hprev[DOUTD];            // 2 KB
    __shared__ float gsum[NR];
    __shared__ float bl[NR];

    int b = blockIdx.x;        // 0..15
    int tid = threadIdx.x;     // 0..1023
    int wave = tid >> 6, lane = tid & 63;
    int jbase = b * JPB;

    // stage my 96 rows of w_hh, RNE-rounded to bf16.
    for (int e = tid; e < NR * DOUTD; e += 1024) {
        int rr = e >> 9, k = e & 511;
        int g = rr / JPB, jj = rr % JPB;
        float v = whh[(size_t)(g * DOUTD + jbase + jj) * DOUTD + k];
        unsigned int u = __float_as_uint(v);
        u += 0x7fffu + ((u >> 16) & 1u);      // round-to-nearest-even
        w[rr][k] = (unsigned short)(u >> 16);
    }
    if (tid < NR) {
        int g = tid / JPB, jj = tid % JPB;
        bl[tid] = bhh[g * DOUTD + jbase + jj];
    }
    for (int k = tid; k < DOUTD; k += 1024) hprev[k] = 0.f;
    __syncthreads();

    long budget = 2L * 1000 * 1000;   // lifetime spin budget: deadlock -> numeric fail

    for (int s = 0; s < TT; ++s) {
        if (s > 0) {
            // wave `wave` waits on producer block bb = wave (relaxed busy poll,
            // no acquire-invalidate, no sleep)
            int bb = wave;
            if (lane == 0) {
                while (__hip_atomic_load(&flags[bb * FLAG_STRIDE], __ATOMIC_RELAXED,
                                         __HIP_MEMORY_SCOPE_AGENT) < s) {
                    if (--budget < 0) break;
                }
            }
            // data loads bypass L1/L2 (relaxed agent atomics) -> fresh from fabric
            if (lane < JPB) {
                int kk = bb * JPB + lane;
                hprev[kk] = __hip_atomic_load(&hs[(size_t)(s - 1) * DOUTD + kk],
                                              __ATOMIC_RELAXED, __HIP_MEMORY_SCOPE_AGENT);
            }
            __syncthreads();   // barrier A: all chunks in hprev
        }

        // matvec: 96 rows over 16 waves -> 6 rows/wave
        #pragma unroll
        for (int rv = 0; rv < 6; ++rv) {
            int rr = wave * 6 + rv;
            float acc = 0.f;
            #pragma unroll
            for (int m = 0; m < 8; ++m) {
                int k = lane + (m << 6);
                float wv = __uint_as_float((unsigned int)w[rr][k] << 16);
                acc = fmaf(wv, hprev[k], acc);
            }
            for (int o = 32; o; o >>= 1) acc += __shfl_down(acc, o, 64);
            if (lane == 0) gsum[rr] = acc + bl[rr];
        }
        // snapshot own h before barrier B (next step's hprev writes are pre-A and
        // could overwrite hprev[jbase..] while wave 0 runs the gate code post-B)
        float hown = (tid < JPB) ? hprev[jbase + tid] : 0.f;
        __syncthreads();       // barrier B: gsum complete; no hprev reads after this

        if (tid < JPB) {       // wave 0, lanes 0..31
            int j = jbase + tid;
            const float* girow = gi + (size_t)s * G3;
            float gr  = girow[j]             + gsum[tid];
            float gz  = girow[DOUTD + j]     + gsum[JPB + tid];
            float gni = girow[2 * DOUTD + j];
            float ghn = gsum[2 * JPB + tid];
            float r = 1.f / (1.f + expf(-gr));
            float z = 1.f / (1.f + expf(-gz));
            float n = tanhf(gni + r * ghn);
            float hn = (1.f - z) * n + z * hown;
            // write-through store (relaxed agent): visible at the coherence point
            __hip_atomic_store(&hs[(size_t)s * DOUTD + j], hn,
                               __ATOMIC_RELAXED, __HIP_MEMORY_SCOPE_AGENT);
        }
        if (wave == 0) {
            // drain the hs stores to the fabric before publishing the flag;
            // same wave as the stores and the flag store -> program order suffices
            asm volatile("s_waitcnt vmcnt(0)" ::: "memory");
            if (lane == 0)
                __hip_atomic_store(&flags[b * FLAG_STRIDE], s + 1,
                                   __ATOMIC_RELAXED, __HIP_MEMORY_SCOPE_AGENT);
        }
        // no global barrier: rows of hs are never reused, flags are monotone
    }
}

// ---------------- attention epilogue ----------------
__global__ void attn_kernel(const float* __restrict__ hs, const float* __restrict__ q,
                            const float* __restrict__ log_lam, float* __restrict__ out) {
    int tid = threadIdx.x;   // 512
    int wave = tid >> 6, lane = tid & 63;
    __shared__ float sc[TT];
    __shared__ float at[TT];
    __shared__ float red[8];
    __shared__ float red2[8];
    __shared__ float denom_s, mx_s;

    const float qscale = 0.04419417382415921757f;  // 1/sqrt(512)
    for (int r = wave; r < TT; r += 8) {
        float acc = 0.f;
        #pragma unroll
        for (int m = 0; m < 8; ++m) {
            int k = lane + 64 * m;
            acc = fmaf(hs[(size_t)r * DOUTD + k], q[k], acc);
        }
        for (int o = 32; o; o >>= 1) acc += __shfl_down(acc, o, 64);
        if (lane == 0) sc[r] = acc * qscale;
    }
    __syncthreads();
    float lam = fmaxf(expf(log_lam[0]), 1e-4f);
    float s_i = sc[tid] - lam * (float)(TT - 1 - tid);

    float mval = s_i;
    for (int o = 32; o; o >>= 1) mval = fmaxf(mval, __shfl_down(mval, o, 64));
    if (lane == 0) red[wave] = mval;
    __syncthreads();
    if (tid == 0) {
        float mm = red[0];
        for (int i = 1; i < 8; ++i) mm = fmaxf(mm, red[i]);
        mx_s = mm;
    }
    __syncthreads();
    float e = expf(s_i - mx_s);
    float ssum = e;
    for (int o = 32; o; o >>= 1) ssum += __shfl_down(ssum, o, 64);
    if (lane == 0) red2[wave] = ssum;
    __syncthreads();
    if (tid == 0) {
        float dsum = 0.f;
        for (int i = 0; i < 8; ++i) dsum += red2[i];
        denom_s = dsum;
    }
    __syncthreads();
    float attn = e / denom_s;
    out[DOUTD + tid] = attn;     // output 1: attn (T,)
    at[tid] = attn;
    __syncthreads();
    // summary[d]: coalesced across d for each row i
    float acc = 0.f;
    for (int i = 0; i < TT; ++i) acc = fmaf(at[i], hs[(size_t)i * DOUTD + tid], acc);
    out[tid] = acc;              // output 0: summary (1, 512)
}

extern "C" void kernel_launch(void* const* d_in, const int* in_sizes, int n_in,
                              void* d_out, int out_size, void* d_ws, size_t ws_size,
                              hipStream_t stream) {
    const int*   idx    = (const int*)d_in[0];
    const float* timef  = (const float*)d_in[1];
    const float* emb    = (const float*)d_in[2];
    const float* latlon = (const float*)d_in[3];
    const float* lnw    = (const float*)d_in[4];
    const float* lnb    = (const float*)d_in[5];
    const float* w1     = (const float*)d_in[6];
    const float* b1     = (const float*)d_in[7];
    const float* w2     = (const float*)d_in[8];
    const float* b2     = (const float*)d_in[9];
    const float* wih    = (const float*)d_in[10];  // (1536, 256)
    const float* whh    = (const float*)d_in[11];  // (1536, 512)
    const float* bih    = (const float*)d_in[12];  // (1536,)
    const float* bhh    = (const float*)d_in[13];  // (1536,)
    const float* q      = (const float*)d_in[14];
    const float* loglam = (const float*)d_in[15];
    float* out = (float*)d_out;

    int*   flags = (int*)d_ws;              // GB*FLAG_STRIDE ints = 4 KB
    float* ws   = (float*)d_ws + GB * FLAG_STRIDE;
    float* feat = ws;                       // 2048
    float* xn   = feat + 2048;              // 512*260 = 133120
    float* h1   = xn + 133120;              // 512*356 = 182272
    float* x2   = h1 + 182272;              // 512*256 = 131072
    float* gi   = x2 + 131072;              // 512*1536 = 786432
    float* hs   = gi + 786432;              // 512*512 = 262144

    feat_kernel<<<1, TT, 0, stream>>>(idx, timef, latlon, feat);
    ln_kernel<<<TT, 256, 0, stream>>>(idx, emb, feat, lnw, lnb, xn);
    mlp1_kernel<<<TT, 384, 0, stream>>>(xn, w1, b1, h1);
    mlp2_kernel<<<TT, 256, 0, stream>>>(h1, w2, b2, x2);
    gi_kernel<<<TT, 256, 0, stream>>>(x2, wih, bih, gi);
    zero_kernel<<<1, GB * FLAG_STRIDE, 0, stream>>>(flags, GB * FLAG_STRIDE);

    void* gru_args[] = { (void*)&gi, (void*)&whh, (void*)&bhh, (void*)&hs, (void*)&flags };
    hipLaunchCooperativeKernel((void*)gru_flag_kernel, dim3(GB), dim3(1024),
                               gru_args, 0, stream);

    attn_kernel<<<1, TT, 0, stream>>>(hs, q, loglam, out);
}